// Round 8
// baseline (273.704 us; speedup 1.0000x reference)
//
#include <hip/hip_runtime.h>
#include <cstdint>
#include <cstddef>

// ---------------------------------------------------------------------------
// GCN 3-layer forward, CSR-gather formulation:
//   out[d] = dinv[d] * ( sum_{s in N(d)} T'[s] + T'[d] ) + b,
//   with T'[r] = dinv[r] * (X[r] @ W)   (scale fused into matmul epilogue).
// CSR build: 2-level bucket counting sort, all fine-grained atomics in LDS.
// Round 7: T' stored as bf16 (RNE), fp32 accumulation everywhere. Rounds 4/6
// lesson: gather is traffic-bound at the L2-miss/fabric tier (~3.4 TB/s,
// dur == FETCH/3.4TBps for two different issue structures) -> halve the
// compulsory row-read bytes. Gather reverted to round-5 shape (11% VALU).
// ---------------------------------------------------------------------------

#define CH 4096      // edges per S1/S3 block
#define BSHIFT 9     // 512 dsts per bucket
#define BSIZE 512
// assumes n <= 131072 (src fits 17 bits, NB <= 256); n = 100000 here.

__device__ __forceinline__ int eidx_at(const void* p, long long i, int is64) {
  if (is64) return (int)((const long long*)p)[i];
  return ((const int*)p)[i];
}

__device__ __forceinline__ unsigned short f2bf(float f) {
  unsigned u = __float_as_uint(f);
  unsigned r = (u + 0x7FFFu + ((u >> 16) & 1u)) >> 16;   // RNE
  return (unsigned short)r;
}
__device__ __forceinline__ float bf2f(unsigned short h) {
  return __uint_as_float((unsigned)h << 16);
}

__global__ void k_flag(const void* eidx, int* flag) {
  const unsigned long long* p = (const unsigned long long*)eidx;
  int lane = threadIdx.x & 63;
  int bad = 0;
#pragma unroll
  for (int i = 0; i < 4; ++i) bad |= (p[lane + 64 * i] > 1000000000ULL) ? 1 : 0;
  int any_bad = __any(bad);
  if (lane == 0) *flag = any_bad ? 0 : 1;
}

// S1: per-block histogram over buckets (LDS atomics only)
__global__ __launch_bounds__(256) void k_s1(const void* eidx, const int* flag,
                                            int* __restrict__ blk_off,
                                            int* __restrict__ bucket_tot,
                                            int E, int NB) {
  __shared__ int h[256];
  int t = threadIdx.x, blk = blockIdx.x;
  if (t < NB) h[t] = 0;
  __syncthreads();
  int is64 = *flag;
  int lo = blk * CH, hi = min(lo + CH, E);
  for (int i = lo + t; i < hi; i += 256) {
    int d = eidx_at(eidx, (long long)E + i, is64);
    atomicAdd(&h[d >> BSHIFT], 1);
  }
  __syncthreads();
  if (t < NB) {
    blk_off[(size_t)blk * NB + t] = h[t];
    atomicAdd(&bucket_tot[t], h[t]);
  }
}

// S2a: exclusive scan of bucket totals (NB <= 256)
__global__ __launch_bounds__(256) void k_s2a(const int* __restrict__ bucket_tot,
                                             int* __restrict__ bucket_base,
                                             int* __restrict__ rowptr,
                                             int NB, int n, int E) {
  int t = threadIdx.x;
  __shared__ int sh[256];
  int v = (t < NB) ? bucket_tot[t] : 0;
  sh[t] = v;
  __syncthreads();
  for (int off = 1; off < 256; off <<= 1) {
    int x = (t >= off) ? sh[t - off] : 0;
    __syncthreads();
    sh[t] += x;
    __syncthreads();
  }
  if (t < NB) bucket_base[t] = sh[t] - v;
  if (t == 0) { bucket_base[NB] = E; rowptr[n] = E; }
}

// S2b: per bucket, scan its per-block counts -> exclusive write ranges
__global__ __launch_bounds__(256) void k_s2b(int* __restrict__ blk_off,
                                             const int* __restrict__ bucket_base,
                                             int nblk, int NB) {
  int b = blockIdx.x, t = threadIdx.x;
  __shared__ int sh[256];
  __shared__ int carry;
  if (t == 0) carry = bucket_base[b];
  __syncthreads();
  for (int tile = 0; tile < nblk; tile += 256) {
    int i = tile + t;
    int v = (i < nblk) ? blk_off[(size_t)i * NB + b] : 0;
    sh[t] = v;
    __syncthreads();
    for (int off = 1; off < 256; off <<= 1) {
      int x = (t >= off) ? sh[t - off] : 0;
      __syncthreads();
      sh[t] += x;
      __syncthreads();
    }
    int c = carry;
    if (i < nblk) blk_off[(size_t)i * NB + b] = c + sh[t] - v;
    int tot = sh[255];
    __syncthreads();
    if (t == 0) carry = c + tot;
    __syncthreads();
  }
}

// S3: scatter packed edges into this block's disjoint bucket ranges
__global__ __launch_bounds__(256) void k_s3(const void* eidx, const int* flag,
                                            const int* __restrict__ blk_off,
                                            unsigned int* __restrict__ packed,
                                            int E, int NB) {
  __shared__ int cur[256];
  int t = threadIdx.x, blk = blockIdx.x;
  if (t < NB) cur[t] = blk_off[(size_t)blk * NB + t];
  __syncthreads();
  int is64 = *flag;
  int lo = blk * CH, hi = min(lo + CH, E);
  for (int i = lo + t; i < hi; i += 256) {
    int s = eidx_at(eidx, i, is64);
    int d = eidx_at(eidx, (long long)E + i, is64);
    int pos = atomicAdd(&cur[d >> BSHIFT], 1);  // LDS atomic
    packed[pos] = ((unsigned)(d & (BSIZE - 1)) << 17) | (unsigned)s;
  }
}

// S4: one block per bucket. LDS hist over 512 local dsts -> rowptr/dinv
// (coalesced), then scatter csr_src within the bucket's window.
__global__ __launch_bounds__(256) void k_s4(const unsigned int* __restrict__ packed,
                                            const int* __restrict__ bucket_base,
                                            int* __restrict__ rowptr,
                                            float* __restrict__ dinv,
                                            int* __restrict__ csr_src, int n) {
  int b = blockIdx.x, t = threadIdx.x;
  int lo = bucket_base[b], hi = bucket_base[b + 1];
  __shared__ int h[BSIZE];
  __shared__ int ps[256];
  __shared__ int cur[BSIZE];
  h[2 * t] = 0; h[2 * t + 1] = 0;
  __syncthreads();
  for (int i = lo + t; i < hi; i += 256)
    atomicAdd(&h[packed[i] >> 17], 1);
  __syncthreads();
  int a0 = h[2 * t], a1 = h[2 * t + 1];
  ps[t] = a0 + a1;
  __syncthreads();
  for (int off = 1; off < 256; off <<= 1) {
    int x = (t >= off) ? ps[t - off] : 0;
    __syncthreads();
    ps[t] += x;
    __syncthreads();
  }
  int pexcl = ps[t] - (a0 + a1);
  int e0 = lo + pexcl, e1 = lo + pexcl + a0;
  cur[2 * t] = e0;
  cur[2 * t + 1] = e1;
  int node0 = b * BSIZE + 2 * t, node1 = b * BSIZE + 2 * t + 1;
  if (node0 < n) { rowptr[node0] = e0; dinv[node0] = rsqrtf((float)(a0 + 1)); }
  if (node1 < n) { rowptr[node1] = e1; dinv[node1] = rsqrtf((float)(a1 + 1)); }
  __syncthreads();
  for (int i = lo + t; i < hi; i += 256) {
    unsigned p = packed[i];
    int j = p >> 17;
    int s = (int)(p & 0x1FFFFu);
    int pos = atomicAdd(&cur[j], 1);  // LDS atomic
    csr_src[pos] = s;
  }
}

// T'[r] = bf16( dinv[r] * (X[r] @ W) ).  One thread per row; W in LDS.
template <int COUT>
__global__ __launch_bounds__(256) void k_matmul(const float* __restrict__ X,
                                                const float* __restrict__ W,
                                                const float* __restrict__ dinv,
                                                unsigned short* __restrict__ T, int n) {
  const int C4 = COUT / 4;
  __shared__ float4 Ws[64 * C4];
  for (int i = threadIdx.x; i < 64 * C4; i += blockDim.x)
    Ws[i] = ((const float4*)W)[i];
  __syncthreads();
  int r = blockIdx.x * blockDim.x + threadIdx.x;
  if (r >= n) return;
  float4 acc[C4];
#pragma unroll
  for (int j = 0; j < C4; ++j) acc[j] = make_float4(0.f, 0.f, 0.f, 0.f);
  const float4* xr = (const float4*)(X + (size_t)r * 64);
#pragma unroll
  for (int k4 = 0; k4 < 16; ++k4) {
    float4 xv = xr[k4];
    const float xs[4] = {xv.x, xv.y, xv.z, xv.w};
#pragma unroll
    for (int c = 0; c < 4; ++c) {
      float xk = xs[c];
      const float4* wrow = &Ws[(k4 * 4 + c) * C4];
#pragma unroll
      for (int j = 0; j < C4; ++j) {
        float4 w = wrow[j];
        acc[j].x = fmaf(xk, w.x, acc[j].x);
        acc[j].y = fmaf(xk, w.y, acc[j].y);
        acc[j].z = fmaf(xk, w.z, acc[j].z);
        acc[j].w = fmaf(xk, w.w, acc[j].w);
      }
    }
  }
  float dr = dinv[r];
  unsigned pk[COUT / 2];
#pragma unroll
  for (int j = 0; j < C4; ++j) {
    pk[2 * j]     = (unsigned)f2bf(acc[j].x * dr) | ((unsigned)f2bf(acc[j].y * dr) << 16);
    pk[2 * j + 1] = (unsigned)f2bf(acc[j].z * dr) | ((unsigned)f2bf(acc[j].w * dr) << 16);
  }
  uint4* tr = (uint4*)(T + (size_t)r * COUT);
#pragma unroll
  for (int q = 0; q < COUT / 8; ++q)
    tr[q] = make_uint4(pk[4 * q], pk[4 * q + 1], pk[4 * q + 2], pk[4 * q + 3]);
}

// One wave per dst row: acc = sum T'[src[j]] (batched 8/4/1, independent
// bf16 loads, fp32 accumulate), then out = dinv*(acc + T'[row]) + b.
template <int COUT, bool RELU>
__global__ __launch_bounds__(256) void k_gather(const unsigned short* __restrict__ T,
                                                const int* __restrict__ rowptr,
                                                const int* __restrict__ csr_src,
                                                const float* __restrict__ dinv,
                                                const float* __restrict__ b,
                                                float* __restrict__ out, int n) {
  int wave = blockIdx.x * (blockDim.x >> 6) + (threadIdx.x >> 6);
  int lane = threadIdx.x & 63;
  int row = __builtin_amdgcn_readfirstlane(wave);
  if (row >= n) return;
  int beg = rowptr[row];
  int end = rowptr[row + 1];
  float dr = dinv[row];
  float a0 = 0.f, a1 = 0.f, a2 = 0.f, a3 = 0.f;
  int j = beg;
  if (lane < COUT) {
    for (; j + 8 <= end; j += 8) {
      int s0 = csr_src[j + 0], s1 = csr_src[j + 1], s2 = csr_src[j + 2], s3 = csr_src[j + 3];
      int s4 = csr_src[j + 4], s5 = csr_src[j + 5], s6 = csr_src[j + 6], s7 = csr_src[j + 7];
      float t0 = bf2f(T[(size_t)s0 * COUT + lane]);
      float t1 = bf2f(T[(size_t)s1 * COUT + lane]);
      float t2 = bf2f(T[(size_t)s2 * COUT + lane]);
      float t3 = bf2f(T[(size_t)s3 * COUT + lane]);
      float t4 = bf2f(T[(size_t)s4 * COUT + lane]);
      float t5 = bf2f(T[(size_t)s5 * COUT + lane]);
      float t6 = bf2f(T[(size_t)s6 * COUT + lane]);
      float t7 = bf2f(T[(size_t)s7 * COUT + lane]);
      a0 += t0; a1 += t1; a2 += t2; a3 += t3;
      a0 += t4; a1 += t5; a2 += t6; a3 += t7;
    }
    if (j + 4 <= end) {
      int s0 = csr_src[j + 0], s1 = csr_src[j + 1], s2 = csr_src[j + 2], s3 = csr_src[j + 3];
      float t0 = bf2f(T[(size_t)s0 * COUT + lane]);
      float t1 = bf2f(T[(size_t)s1 * COUT + lane]);
      float t2 = bf2f(T[(size_t)s2 * COUT + lane]);
      float t3 = bf2f(T[(size_t)s3 * COUT + lane]);
      a0 += t0; a1 += t1; a2 += t2; a3 += t3;
      j += 4;
    }
    for (; j < end; ++j) {
      int s = csr_src[j];
      a0 += bf2f(T[(size_t)s * COUT + lane]);
    }
    float acc = (a0 + a1) + (a2 + a3);
    float v = fmaf(dr, acc + bf2f(T[(size_t)row * COUT + lane]), b[lane]);
    if (RELU) v = fmaxf(v, 0.f);
    out[(size_t)row * COUT + lane] = v;
  }
}

extern "C" void kernel_launch(void* const* d_in, const int* in_sizes, int n_in,
                              void* d_out, int out_size, void* d_ws, size_t ws_size,
                              hipStream_t stream) {
  const float* x  = (const float*)d_in[0];
  const void*  ei = d_in[1];
  const float* W1 = (const float*)d_in[2];
  const float* b1 = (const float*)d_in[3];
  const float* W2 = (const float*)d_in[4];
  const float* b2 = (const float*)d_in[5];
  const float* W3 = (const float*)d_in[6];
  const float* b3 = (const float*)d_in[7];
  float* out = (float*)d_out;

  const int n = in_sizes[0] / 64;   // 100000
  const int E = in_sizes[1] / 2;    // 1000000

  const int NB   = (n + BSIZE - 1) / BSIZE;  // 196 buckets
  const int NBLK = (E + CH - 1) / CH;        // 245 edge blocks

  char* ws = (char*)d_ws;
  size_t off = 0;
  auto carve = [&](size_t bytes) -> void* {
    void* p = ws + off;
    off = (off + bytes + 255) & ~(size_t)255;
    return p;
  };
  int*            flag        = (int*)carve(16);
  float*          dinv        = (float*)carve(sizeof(float) * n);
  int*            rowptr      = (int*)carve(sizeof(int) * (n + 1));
  int*            bucket_tot  = (int*)carve(sizeof(int) * 256);
  int*            bucket_base = (int*)carve(sizeof(int) * 257);
  int*            blk_off     = (int*)carve(sizeof(int) * (size_t)NBLK * NB);
  unsigned*       packed      = (unsigned*)carve(sizeof(unsigned) * E);
  int*            csr_src     = (int*)carve(sizeof(int) * E);
  unsigned short* T           = (unsigned short*)carve(sizeof(unsigned short) * (size_t)n * 64);
  float*          A           = (float*)carve(sizeof(float) * (size_t)n * 64);

  const int B = 256;
  const int gN = (n + B - 1) / B;
  const int gW = (n + 3) / 4;  // 4 waves/block, 1 wave/row

  // ---- CSR build (bucket counting sort; no global fine-grained atomics) ----
  k_flag<<<1, 64, 0, stream>>>(ei, flag);
  hipMemsetAsync(bucket_tot, 0, sizeof(int) * NB, stream);
  k_s1<<<NBLK, B, 0, stream>>>(ei, flag, blk_off, bucket_tot, E, NB);
  k_s2a<<<1, B, 0, stream>>>(bucket_tot, bucket_base, rowptr, NB, n, E);
  k_s2b<<<NB, B, 0, stream>>>(blk_off, bucket_base, NBLK, NB);
  k_s3<<<NBLK, B, 0, stream>>>(ei, flag, blk_off, packed, E, NB);
  k_s4<<<NB, B, 0, stream>>>(packed, bucket_base, rowptr, dinv, csr_src, n);

  // ---- layer 1: x -> A ----
  k_matmul<64><<<gN, B, 0, stream>>>(x, W1, dinv, T, n);
  k_gather<64, true><<<gW, B, 0, stream>>>(T, rowptr, csr_src, dinv, b1, A, n);

  // ---- layer 2: A -> A ----
  k_matmul<64><<<gN, B, 0, stream>>>(A, W2, dinv, T, n);
  k_gather<64, true><<<gW, B, 0, stream>>>(T, rowptr, csr_src, dinv, b2, A, n);

  // ---- layer 3: A -> out ----
  k_matmul<32><<<gN, B, 0, stream>>>(A, W3, dinv, T, n);
  k_gather<32, false><<<gW, B, 0, stream>>>(T, rowptr, csr_src, dinv, b3, out, n);
}

// Round 9
// 196.772 us; speedup vs baseline: 1.3910x; 1.3910x over previous
//
#include <hip/hip_runtime.h>
#include <cstdint>
#include <cstddef>

// ---------------------------------------------------------------------------
// GCN 3-layer forward, CSR-gather formulation:
//   out[d] = dinv[d] * ( sum_{s in N(d)} T'[s] + T'[d] ) + b,
//   with T'[r] = bf16( dinv[r] * (X[r] @ W) ).
// CSR build: 2-level bucket counting sort, all fine-grained atomics in LDS.
// Round 8: matmul -> MFMA (16x16x32 bf16), one wave per 16 rows, no LDS.
// fp32 accuracy kept via compensated split: X=Xh+Xl, W=Wh+Wl (bf16 pairs),
// acc = XhWh + XhWl + XlWh (error ~2^-17). Round-7 matmul was occupancy-
// bound (13.5% occ, 391 heavyweight blocks, 50us for a 10us problem).
// ---------------------------------------------------------------------------

#define CH 4096      // edges per S1/S3 block
#define BSHIFT 9     // 512 dsts per bucket
#define BSIZE 512
// assumes n <= 131072 (src fits 17 bits, NB <= 256); n = 100000 here.

typedef short bf16x8 __attribute__((ext_vector_type(8)));
typedef float f32x4 __attribute__((ext_vector_type(4)));

__device__ __forceinline__ int eidx_at(const void* p, long long i, int is64) {
  if (is64) return (int)((const long long*)p)[i];
  return ((const int*)p)[i];
}

__device__ __forceinline__ unsigned short f2bf(float f) {
  unsigned u = __float_as_uint(f);
  unsigned r = (u + 0x7FFFu + ((u >> 16) & 1u)) >> 16;   // RNE
  return (unsigned short)r;
}
__device__ __forceinline__ float bf2f(unsigned short h) {
  return __uint_as_float((unsigned)h << 16);
}

__global__ void k_flag(const void* eidx, int* flag) {
  const unsigned long long* p = (const unsigned long long*)eidx;
  int lane = threadIdx.x & 63;
  int bad = 0;
#pragma unroll
  for (int i = 0; i < 4; ++i) bad |= (p[lane + 64 * i] > 1000000000ULL) ? 1 : 0;
  int any_bad = __any(bad);
  if (lane == 0) *flag = any_bad ? 0 : 1;
}

// S1: per-block histogram over buckets (LDS atomics only)
__global__ __launch_bounds__(256) void k_s1(const void* eidx, const int* flag,
                                            int* __restrict__ blk_off,
                                            int* __restrict__ bucket_tot,
                                            int E, int NB) {
  __shared__ int h[256];
  int t = threadIdx.x, blk = blockIdx.x;
  if (t < NB) h[t] = 0;
  __syncthreads();
  int is64 = *flag;
  int lo = blk * CH, hi = min(lo + CH, E);
  for (int i = lo + t; i < hi; i += 256) {
    int d = eidx_at(eidx, (long long)E + i, is64);
    atomicAdd(&h[d >> BSHIFT], 1);
  }
  __syncthreads();
  if (t < NB) {
    blk_off[(size_t)blk * NB + t] = h[t];
    atomicAdd(&bucket_tot[t], h[t]);
  }
}

// S2a: exclusive scan of bucket totals (NB <= 256)
__global__ __launch_bounds__(256) void k_s2a(const int* __restrict__ bucket_tot,
                                             int* __restrict__ bucket_base,
                                             int* __restrict__ rowptr,
                                             int NB, int n, int E) {
  int t = threadIdx.x;
  __shared__ int sh[256];
  int v = (t < NB) ? bucket_tot[t] : 0;
  sh[t] = v;
  __syncthreads();
  for (int off = 1; off < 256; off <<= 1) {
    int x = (t >= off) ? sh[t - off] : 0;
    __syncthreads();
    sh[t] += x;
    __syncthreads();
  }
  if (t < NB) bucket_base[t] = sh[t] - v;
  if (t == 0) { bucket_base[NB] = E; rowptr[n] = E; }
}

// S2b: per bucket, scan its per-block counts -> exclusive write ranges
__global__ __launch_bounds__(256) void k_s2b(int* __restrict__ blk_off,
                                             const int* __restrict__ bucket_base,
                                             int nblk, int NB) {
  int b = blockIdx.x, t = threadIdx.x;
  __shared__ int sh[256];
  __shared__ int carry;
  if (t == 0) carry = bucket_base[b];
  __syncthreads();
  for (int tile = 0; tile < nblk; tile += 256) {
    int i = tile + t;
    int v = (i < nblk) ? blk_off[(size_t)i * NB + b] : 0;
    sh[t] = v;
    __syncthreads();
    for (int off = 1; off < 256; off <<= 1) {
      int x = (t >= off) ? sh[t - off] : 0;
      __syncthreads();
      sh[t] += x;
      __syncthreads();
    }
    int c = carry;
    if (i < nblk) blk_off[(size_t)i * NB + b] = c + sh[t] - v;
    int tot = sh[255];
    __syncthreads();
    if (t == 0) carry = c + tot;
    __syncthreads();
  }
}

// S3: scatter packed edges into this block's disjoint bucket ranges
__global__ __launch_bounds__(256) void k_s3(const void* eidx, const int* flag,
                                            const int* __restrict__ blk_off,
                                            unsigned int* __restrict__ packed,
                                            int E, int NB) {
  __shared__ int cur[256];
  int t = threadIdx.x, blk = blockIdx.x;
  if (t < NB) cur[t] = blk_off[(size_t)blk * NB + t];
  __syncthreads();
  int is64 = *flag;
  int lo = blk * CH, hi = min(lo + CH, E);
  for (int i = lo + t; i < hi; i += 256) {
    int s = eidx_at(eidx, i, is64);
    int d = eidx_at(eidx, (long long)E + i, is64);
    int pos = atomicAdd(&cur[d >> BSHIFT], 1);  // LDS atomic
    packed[pos] = ((unsigned)(d & (BSIZE - 1)) << 17) | (unsigned)s;
  }
}

// S4: one block per bucket. LDS hist over 512 local dsts -> rowptr/dinv
// (coalesced), then scatter csr_src within the bucket's window.
__global__ __launch_bounds__(256) void k_s4(const unsigned int* __restrict__ packed,
                                            const int* __restrict__ bucket_base,
                                            int* __restrict__ rowptr,
                                            float* __restrict__ dinv,
                                            int* __restrict__ csr_src, int n) {
  int b = blockIdx.x, t = threadIdx.x;
  int lo = bucket_base[b], hi = bucket_base[b + 1];
  __shared__ int h[BSIZE];
  __shared__ int ps[256];
  __shared__ int cur[BSIZE];
  h[2 * t] = 0; h[2 * t + 1] = 0;
  __syncthreads();
  for (int i = lo + t; i < hi; i += 256)
    atomicAdd(&h[packed[i] >> 17], 1);
  __syncthreads();
  int a0 = h[2 * t], a1 = h[2 * t + 1];
  ps[t] = a0 + a1;
  __syncthreads();
  for (int off = 1; off < 256; off <<= 1) {
    int x = (t >= off) ? ps[t - off] : 0;
    __syncthreads();
    ps[t] += x;
    __syncthreads();
  }
  int pexcl = ps[t] - (a0 + a1);
  int e0 = lo + pexcl, e1 = lo + pexcl + a0;
  cur[2 * t] = e0;
  cur[2 * t + 1] = e1;
  int node0 = b * BSIZE + 2 * t, node1 = b * BSIZE + 2 * t + 1;
  if (node0 < n) { rowptr[node0] = e0; dinv[node0] = rsqrtf((float)(a0 + 1)); }
  if (node1 < n) { rowptr[node1] = e1; dinv[node1] = rsqrtf((float)(a1 + 1)); }
  __syncthreads();
  for (int i = lo + t; i < hi; i += 256) {
    unsigned p = packed[i];
    int j = p >> 17;
    int s = (int)(p & 0x1FFFFu);
    int pos = atomicAdd(&cur[j], 1);  // LDS atomic
    csr_src[pos] = s;
  }
}

// MFMA matmul: T'[r] = bf16(dinv[r] * (X[r] @ W)), one wave per 16 rows.
// Compensated bf16 split for fp32-equivalent accuracy:
//   X = Xh + Xl, W = Wh + Wl;  acc = XhWh + XhWl + XlWh.
// Fragment layouts (m89/m97-verified): A/B lane l holds 8 contiguous k at
// k=(l>>4)*8+i, row/col = l&15; D: col=l&15, row=(l>>4)*4+reg.
// Requires 16 | n.
template <int COUT>
__global__ __launch_bounds__(256) void k_mm(const float* __restrict__ X,
                                            const float* __restrict__ W,
                                            const float* __restrict__ dinv,
                                            unsigned short* __restrict__ T, int n) {
  const int NT = COUT / 16;
  int lane = threadIdx.x & 63;
  int wid = blockIdx.x * (blockDim.x >> 6) + (threadIdx.x >> 6);
  int rowb = wid * 16;
  if (rowb >= n) return;
  int lr = lane & 15;   // A-row / D-col selector
  int lk = lane >> 4;   // k-group selector

  // ---- W fragments (hi/lo), per-lane strided scalar loads (L1/L2-hot) ----
  bf16x8 wh[2 * NT], wl[2 * NT];
#pragma unroll
  for (int kk = 0; kk < 2; ++kk) {
#pragma unroll
    for (int nt = 0; nt < NT; ++nt) {
#pragma unroll
      for (int i = 0; i < 8; ++i) {
        int k = kk * 32 + lk * 8 + i;
        float w = W[k * COUT + nt * 16 + lr];
        unsigned short h = f2bf(w);
        wh[kk * NT + nt][i] = (short)h;
        wl[kk * NT + nt][i] = (short)f2bf(w - bf2f(h));
      }
    }
  }

  // ---- A fragments (hi/lo) from fp32 row, vectorized loads ----
  const float* ar = X + (size_t)(rowb + lr) * 64;
  bf16x8 ah[2], al[2];
#pragma unroll
  for (int kk = 0; kk < 2; ++kk) {
    float4 v0 = *(const float4*)(ar + kk * 32 + lk * 8);
    float4 v1 = *(const float4*)(ar + kk * 32 + lk * 8 + 4);
    float vv[8] = {v0.x, v0.y, v0.z, v0.w, v1.x, v1.y, v1.z, v1.w};
#pragma unroll
    for (int i = 0; i < 8; ++i) {
      unsigned short h = f2bf(vv[i]);
      ah[kk][i] = (short)h;
      al[kk][i] = (short)f2bf(vv[i] - bf2f(h));
    }
  }

  // ---- MFMA: 6 per n-tile (2 k-steps x 3 split terms) ----
  f32x4 acc[NT];
#pragma unroll
  for (int nt = 0; nt < NT; ++nt) {
    f32x4 a = {0.f, 0.f, 0.f, 0.f};
#pragma unroll
    for (int kk = 0; kk < 2; ++kk) {
      a = __builtin_amdgcn_mfma_f32_16x16x32_bf16(ah[kk], wh[kk * NT + nt], a, 0, 0, 0);
      a = __builtin_amdgcn_mfma_f32_16x16x32_bf16(ah[kk], wl[kk * NT + nt], a, 0, 0, 0);
      a = __builtin_amdgcn_mfma_f32_16x16x32_bf16(al[kk], wh[kk * NT + nt], a, 0, 0, 0);
    }
    acc[nt] = a;
  }

  // ---- epilogue: D[m=lk*4+j][n=nt*16+lr] -> dinv scale -> bf16 store ----
#pragma unroll
  for (int j = 0; j < 4; ++j) {
    int row = rowb + lk * 4 + j;
    float dr = dinv[row];
#pragma unroll
    for (int nt = 0; nt < NT; ++nt)
      T[(size_t)row * COUT + nt * 16 + lr] = f2bf(acc[nt][j] * dr);
  }
}

// One wave per dst row: acc = sum T'[src[j]] (batched 8/4/1, independent
// bf16 loads, fp32 accumulate), then out = dinv*(acc + T'[row]) + b.
template <int COUT, bool RELU>
__global__ __launch_bounds__(256) void k_gather(const unsigned short* __restrict__ T,
                                                const int* __restrict__ rowptr,
                                                const int* __restrict__ csr_src,
                                                const float* __restrict__ dinv,
                                                const float* __restrict__ b,
                                                float* __restrict__ out, int n) {
  int wave = blockIdx.x * (blockDim.x >> 6) + (threadIdx.x >> 6);
  int lane = threadIdx.x & 63;
  int row = __builtin_amdgcn_readfirstlane(wave);
  if (row >= n) return;
  int beg = rowptr[row];
  int end = rowptr[row + 1];
  float dr = dinv[row];
  float a0 = 0.f, a1 = 0.f, a2 = 0.f, a3 = 0.f;
  int j = beg;
  if (lane < COUT) {
    for (; j + 8 <= end; j += 8) {
      int s0 = csr_src[j + 0], s1 = csr_src[j + 1], s2 = csr_src[j + 2], s3 = csr_src[j + 3];
      int s4 = csr_src[j + 4], s5 = csr_src[j + 5], s6 = csr_src[j + 6], s7 = csr_src[j + 7];
      float t0 = bf2f(T[(size_t)s0 * COUT + lane]);
      float t1 = bf2f(T[(size_t)s1 * COUT + lane]);
      float t2 = bf2f(T[(size_t)s2 * COUT + lane]);
      float t3 = bf2f(T[(size_t)s3 * COUT + lane]);
      float t4 = bf2f(T[(size_t)s4 * COUT + lane]);
      float t5 = bf2f(T[(size_t)s5 * COUT + lane]);
      float t6 = bf2f(T[(size_t)s6 * COUT + lane]);
      float t7 = bf2f(T[(size_t)s7 * COUT + lane]);
      a0 += t0; a1 += t1; a2 += t2; a3 += t3;
      a0 += t4; a1 += t5; a2 += t6; a3 += t7;
    }
    if (j + 4 <= end) {
      int s0 = csr_src[j + 0], s1 = csr_src[j + 1], s2 = csr_src[j + 2], s3 = csr_src[j + 3];
      float t0 = bf2f(T[(size_t)s0 * COUT + lane]);
      float t1 = bf2f(T[(size_t)s1 * COUT + lane]);
      float t2 = bf2f(T[(size_t)s2 * COUT + lane]);
      float t3 = bf2f(T[(size_t)s3 * COUT + lane]);
      a0 += t0; a1 += t1; a2 += t2; a3 += t3;
      j += 4;
    }
    for (; j < end; ++j) {
      int s = csr_src[j];
      a0 += bf2f(T[(size_t)s * COUT + lane]);
    }
    float acc = (a0 + a1) + (a2 + a3);
    float v = fmaf(dr, acc + bf2f(T[(size_t)row * COUT + lane]), b[lane]);
    if (RELU) v = fmaxf(v, 0.f);
    out[(size_t)row * COUT + lane] = v;
  }
}

extern "C" void kernel_launch(void* const* d_in, const int* in_sizes, int n_in,
                              void* d_out, int out_size, void* d_ws, size_t ws_size,
                              hipStream_t stream) {
  const float* x  = (const float*)d_in[0];
  const void*  ei = d_in[1];
  const float* W1 = (const float*)d_in[2];
  const float* b1 = (const float*)d_in[3];
  const float* W2 = (const float*)d_in[4];
  const float* b2 = (const float*)d_in[5];
  const float* W3 = (const float*)d_in[6];
  const float* b3 = (const float*)d_in[7];
  float* out = (float*)d_out;

  const int n = in_sizes[0] / 64;   // 100000 (multiple of 16)
  const int E = in_sizes[1] / 2;    // 1000000

  const int NB   = (n + BSIZE - 1) / BSIZE;  // 196 buckets
  const int NBLK = (E + CH - 1) / CH;        // 245 edge blocks

  char* ws = (char*)d_ws;
  size_t off = 0;
  auto carve = [&](size_t bytes) -> void* {
    void* p = ws + off;
    off = (off + bytes + 255) & ~(size_t)255;
    return p;
  };
  int*            flag        = (int*)carve(16);
  float*          dinv        = (float*)carve(sizeof(float) * n);
  int*            rowptr      = (int*)carve(sizeof(int) * (n + 1));
  int*            bucket_tot  = (int*)carve(sizeof(int) * 256);
  int*            bucket_base = (int*)carve(sizeof(int) * 257);
  int*            blk_off     = (int*)carve(sizeof(int) * (size_t)NBLK * NB);
  unsigned*       packed      = (unsigned*)carve(sizeof(unsigned) * E);
  int*            csr_src     = (int*)carve(sizeof(int) * E);
  unsigned short* T           = (unsigned short*)carve(sizeof(unsigned short) * (size_t)n * 64);
  float*          A           = (float*)carve(sizeof(float) * (size_t)n * 64);

  const int B = 256;
  const int gW  = (n + 3) / 4;                    // gather: 4 waves/block
  const int gMM = ((n + 15) / 16 + 3) / 4;        // mfma: 4 waves/block, 16 rows/wave

  // ---- CSR build (bucket counting sort; no global fine-grained atomics) ----
  k_flag<<<1, 64, 0, stream>>>(ei, flag);
  hipMemsetAsync(bucket_tot, 0, sizeof(int) * NB, stream);
  k_s1<<<NBLK, B, 0, stream>>>(ei, flag, blk_off, bucket_tot, E, NB);
  k_s2a<<<1, B, 0, stream>>>(bucket_tot, bucket_base, rowptr, NB, n, E);
  k_s2b<<<NB, B, 0, stream>>>(blk_off, bucket_base, NBLK, NB);
  k_s3<<<NBLK, B, 0, stream>>>(ei, flag, blk_off, packed, E, NB);
  k_s4<<<NB, B, 0, stream>>>(packed, bucket_base, rowptr, dinv, csr_src, n);

  // ---- layer 1: x -> A ----
  k_mm<64><<<gMM, B, 0, stream>>>(x, W1, dinv, T, n);
  k_gather<64, true><<<gW, B, 0, stream>>>(T, rowptr, csr_src, dinv, b1, A, n);

  // ---- layer 2: A -> A ----
  k_mm<64><<<gMM, B, 0, stream>>>(A, W2, dinv, T, n);
  k_gather<64, true><<<gW, B, 0, stream>>>(T, rowptr, csr_src, dinv, b2, A, n);

  // ---- layer 3: A -> out ----
  k_mm<32><<<gMM, B, 0, stream>>>(A, W3, dinv, T, n);
  k_gather<32, false><<<gW, B, 0, stream>>>(T, rowptr, csr_src, dinv, b3, out, n);
}